// Round 14
// baseline (44.123 us; speedup 1.0000x reference)
//
#include <hip/hip_runtime.h>
#include <hip/hip_bf16.h>
#include <stdint.h>

// out[b][co][y][x0] = sum_{ci,ky,kx} x[b][ci][(y+ky-3)%256][(x0+kx-3)%256] * d[b][co][ci][ky][kx]
// Per (b,y-tile) GEMM: tmp[u][n=co*8+kx] = sum_{ci,ky} X[ci][(y+ky-3)%256][u] * w[co][ci][ky][kx]
// epilogue: out[x0] = sum_kx tmp[(x0+kx-3)&255][co*8+kx].  MFMA 32x32x16 bf16 (verified r3-r6,r12).
// v10 "occupancy": r10 PMC showed nothing busy (HBM 21%, Mfma 17%, VALU 20%, Occ 44%) at the
// invariant 4 waves/SIMD of all prior rounds. This round halves per-block LDS to 73.7KB
// (R=4, CIC=4, dbuf) -> 2 blocks/CU x 16 waves = 8 waves/SIMD, grid 512 (2/CU, XCD-pinned).
// acc = 2 x f32x16 = 32 regs; __launch_bounds__(1024,8) holds total <=64 for 32-wave residency.
// Loop structure, swizzle, k-slot mappings byte-identical to v8/v9 (proven stable).

constexpr int NB = 8, CIN = 64, HH = 256, WW = 256, CO = 3, KK = 7;
constexpr int R = 4;               // output rows per block
constexpr int XROWS = 10;          // staged rows (input y0-3 .. y0+6)
constexpr int CIC = 4;             // ci per chunk
constexpr int NCH = CIN / CIC;     // 16
constexpr int XBYTES = XROWS * 256 * 8;      // 20480 per buffer (8B units: [u][ci4] bf16)
constexpr int BOFF   = 2 * XBYTES;           // 40960
constexpr int SMEMSZ = BOFF + 32 * 64 * 16;  // + 32KB B = 73728

typedef short bf16x4 __attribute__((ext_vector_type(4)));
typedef short bf16x8 __attribute__((ext_vector_type(8)));
typedef float f32x16 __attribute__((ext_vector_type(16)));

__device__ inline uint16_t f2bf(float f) {
    union { __hip_bfloat16 h; uint16_t u; } cv;
    cv.h = __float2bfloat16(f);
    return cv.u;
}
// involution on 0..255 (8B-unit index): bits[3:0] ^= bits[7:4]. v8/v9-validated:
// stride-4-unit staging writers cover all 8 bank groups; frag readers broadcast-free.
__device__ inline int uswz(int u) { return u ^ ((u >> 4) & 15); }

__global__ __launch_bounds__(1024, 8)
void conv_mfma_v10(const float* __restrict__ x, const float* __restrict__ d,
                   float* __restrict__ outp) {
    __shared__ char smem[SMEMSZ];
    float* tmp = (float*)smem;                       // epilogue alias [2][256][33]

    const int tid  = threadIdx.x;
    const int lane = tid & 63, wv = tid >> 6;        // 16 waves
    const int y_t  = wv >> 2;                        // row 0..3
    const int xh   = (wv >> 1) & 1;                  // u half
    const int mh   = wv & 1;                         // m-pair within half
    const int l31  = lane & 31, lh = lane >> 5;

    // XCD-pinned: image b = blk%8; 64 adjacent y-tiles per XCD share halos in L2.
    const int blk = blockIdx.x;
    const int b   = blk & 7;
    const int y0  = (blk >> 3) * R;

    const float* xb = x + (size_t)b * CIN * HH * WW;
    const float* db = d + (size_t)b * CO * CIN * KK * KK;

    f32x16 acc[2];
    #pragma unroll
    for (int m = 0; m < 2; ++m)
        #pragma unroll
        for (int i = 0; i < 16; ++i) acc[m][i] = 0.f;

    // ---- unified stage (r5-proven phase): load -> convert -> ds_write ----
    auto stageX = [&](int c, int buf) {
        if (tid < XROWS * 64) {                      // 640 active threads
            const int r = tid >> 6, q = tid & 63;
            const int row = (y0 + r - 3) & (HH - 1);
            const float* p = xb + ((size_t)(c * CIC) * HH + row) * WW + q * 4;
            float4 v0 = *reinterpret_cast<const float4*>(p);
            float4 v1 = *reinterpret_cast<const float4*>(p + (size_t)HH * WW);
            float4 v2 = *reinterpret_cast<const float4*>(p + (size_t)2 * HH * WW);
            float4 v3 = *reinterpret_cast<const float4*>(p + (size_t)3 * HH * WW);
            char* dstb = smem + buf * XBYTES;
            #pragma unroll
            for (int t = 0; t < 4; ++t) {
                uint2 pk;
                pk.x = (uint32_t)f2bf(((const float*)&v0)[t]) | ((uint32_t)f2bf(((const float*)&v1)[t]) << 16);
                pk.y = (uint32_t)f2bf(((const float*)&v2)[t]) | ((uint32_t)f2bf(((const float*)&v3)[t]) << 16);
                const int us = uswz(q * 4 + t);
                *reinterpret_cast<uint2*>(dstb + (size_t)(r * 256 + us) * 8) = pk;
            }
        }
    };

    // ---- compute chunk c: 2 k-steps (ky quads), 2 m-frags ----
    auto compute = [&](int c, int buf) {
        const char* Xb = smem + buf * XBYTES;
        #pragma unroll
        for (int ks2 = 0; ks2 < 2; ++ks2) {
            const int fi = c * 2 + ks2;
            const bf16x8 bfrag = *reinterpret_cast<const bf16x8*>(
                smem + BOFF + (size_t)(fi * 64 + lane) * 16);
            const int r1 = y_t + ks2 * 4 + lh * 2;   // <= 9, in range
            int r2 = r1 + 1;                         // ==10 only (y_t=3,ks2=1,lh=1): ky=7, zero B
            if (r2 >= XROWS) r2 = 0;
            #pragma unroll
            for (int m = 0; m < 2; ++m) {
                const int us = uswz(xh * 128 + (mh * 2 + m) * 32 + l31);
                const bf16x4 lo = *reinterpret_cast<const bf16x4*>(Xb + (size_t)(r1 * 256 + us) * 8);
                const bf16x4 hi = *reinterpret_cast<const bf16x4*>(Xb + (size_t)(r2 * 256 + us) * 8);
                bf16x8 a;
                a[0] = lo[0]; a[1] = lo[1]; a[2] = lo[2]; a[3] = lo[3];
                a[4] = hi[0]; a[5] = hi[1]; a[6] = hi[2]; a[7] = hi[3];
                acc[m] = __builtin_amdgcn_mfma_f32_32x32x16_bf16(a, bfrag, acc[m], 0, 0, 0);
            }
        }
    };

    // ---- prologue: X chunk 0 + all 32 B frags (r6/r12-validated CIC=4 k-slot mapping) ----
    stageX(0, 0);
    #pragma unroll
    for (int k = 0; k < 2; ++k) {
        const int s = tid + k * 1024;                // 2048 slots = 32 frags x 64 lanes
        const int fi = s >> 6, ln = s & 63;
        const int c = fi >> 1, ks2 = fi & 1;
        const int n = ln & 31, lh2 = ln >> 5;
        const int co = n >> 3, kx = n & 7;
        uint16_t vals[8];
        #pragma unroll
        for (int j = 0; j < 8; ++j) {
            const int ky = ks2 * 4 + lh2 * 2 + (j >> 2);
            float v = 0.f;
            if (co < CO && kx < KK && ky < KK)
                v = db[((size_t)co * CIN + c * CIC + (j & 3)) * (KK * KK) + ky * KK + kx];
            vals[j] = f2bf(v);
        }
        uint4 pk;
        pk.x = (uint32_t)vals[0] | ((uint32_t)vals[1] << 16);
        pk.y = (uint32_t)vals[2] | ((uint32_t)vals[3] << 16);
        pk.z = (uint32_t)vals[4] | ((uint32_t)vals[5] << 16);
        pk.w = (uint32_t)vals[6] | ((uint32_t)vals[7] << 16);
        *reinterpret_cast<uint4*>(smem + BOFF + (size_t)(fi * 64 + ln) * 16) = pk;
    }

    // ---- main loop (r5-proven): barrier ; stage(c+1) ; compute(c) ----
    for (int c = 0; c < NCH; ++c) {
        __syncthreads();                             // stage(c) writes visible
        if (c + 1 < NCH) stageX(c + 1, (c + 1) & 1); // opposite buffer
        compute(c, c & 1);
    }

    // ---- epilogue: 2 passes x 2 rows; tmp[2][256][33] = 67584 B aliases Xl+Bl ----
    for (int p = 0; p < 2; ++p) {
        __syncthreads();                             // prior compute/reduce reads done
        if ((y_t >> 1) == p) {
            const int rr = y_t & 1;
            #pragma unroll
            for (int m = 0; m < 2; ++m)
                #pragma unroll
                for (int reg = 0; reg < 16; ++reg) {
                    const int rowloc = (reg & 3) + 8 * (reg >> 2) + 4 * lh;
                    const int u = xh * 128 + (mh * 2 + m) * 32 + rowloc;
                    tmp[((size_t)rr * 256 + u) * 33 + l31] = acc[m][reg];
                }
        }
        __syncthreads();
        #pragma unroll
        for (int it0 = 0; it0 < 2; ++it0) {
            const int it = tid + it0 * 1024;
            if (it < 2 * CO * 256) {                 // 1536 items
                const int rr  = it / (CO * 256);
                const int rem = it - rr * (CO * 256);
                const int co  = rem >> 8, x0 = rem & 255;
                float s = 0.f;
                #pragma unroll
                for (int kx = 0; kx < 7; ++kx)
                    s += tmp[((size_t)rr * 256 + ((x0 + kx - 3) & 255)) * 33 + co * 8 + kx];
                outp[(((size_t)b * CO + co) * HH + (y0 + p * 2 + rr)) * WW + x0] = s;
            }
        }
    }
}

extern "C" void kernel_launch(void* const* d_in, const int* in_sizes, int n_in,
                              void* d_out, int out_size, void* d_ws, size_t ws_size,
                              hipStream_t stream) {
    const float* x = (const float*)d_in[0];
    const float* d = (const float*)d_in[1];
    float* outp = (float*)d_out;
    conv_mfma_v10<<<dim3(NB * (HH / R)), 1024, 0, stream>>>(x, d, outp);
}